// Round 6
// baseline (133.758 us; speedup 1.0000x reference)
//
#include <hip/hip_runtime.h>

// ---------------------------------------------------------------------------
// 3-dispatch gather splat, COLUMN RECORDS + Z-COLUMN CHUNK GATHER.
// History: R7 fat records; R8 9x bin_prep split; R9 LDS staging; R10 atomic
// padding (NULL); R11 column records + x-ladder (bin_prep down, splat VALU-
// bound); R12 stored f32 x-table (splat body 15 VALU/rec, total 123.3).
// R13 (this round): splat restructure — one wave owns 4 consecutive z-tiles
// (unit = tx,ty,zc). Slot lists staged into a 4-deep wave-private LDS ring:
// each slot loaded ONCE, reused by up to 3 tiles (list traffic ~halved), and
// staging is split issue-early/write-late (T14): slot tz+2's global loads are
// issued before tile tz's compute, ds_write after -> HBM latency hidden under
// ~700cy of compute. z0 % 4 == 0 + manual 4-step unroll => all ring indices
// compile-time. Record math byte-identical to R12 => absmax unchanged.
// bin_prep deliberately untouched (decomposition still ambiguous).
// ws use ~50.5 MB (harness d_ws is 256 MiB, poison-filled per iteration).
// ---------------------------------------------------------------------------

#define NTILE 32768           // 32^3 tiles of 8^3 voxels
#define CAP   32              // records per center-slot: avg ~7.7, Poisson-safe
#define LOG2E 1.4426950408889634f

typedef unsigned long long ull;

struct __align__(16) Rec {    // 48 B, one per (gaussian, x-y column)
    float cy, cz, w2;         // voxel-space center y,z; exp2 scale
    unsigned meta;            // [0:8) mnz, [8:16) mxz_incl, [16:19) loy, [19:23) hiy
    float ex[8];              // clipped, intensity-folded x-table (zeros outside)
};

// ---- kernel 1: per-(Gaussian, tx, ty) column record ------------------------
__global__ __launch_bounds__(256) void bin_prep_kernel(
    const float* __restrict__ centers,
    const float* __restrict__ sigmas,
    const float* __restrict__ intens,
    int*  __restrict__ counts,
    Rec*  __restrict__ list,
    int N)
{
    int g = blockIdx.x * 256 + threadIdx.x;
    if (g >= N) return;
    int txi = blockIdx.y % 3;          // wave-uniform
    int tyi = blockIdx.y / 3;

    float cx = centers[3*g+0] * 255.0f;
    float cy = centers[3*g+1] * 255.0f;
    float cz = centers[3*g+2] * 255.0f;
    float sig = sigmas[g];
    float cut = 3.0f * sig * 255.0f;
    float cc[3] = {cx, cy, cz};
    int mn[3], mx[3];
    #pragma unroll
    for (int a = 0; a < 3; ++a) {
        mn[a] = (int)floorf(fmaxf(cc[a] - cut, 0.0f));
        mx[a] = (int)fminf(floorf(fminf(cc[a] + cut, 255.0f)) + 1.0f, 256.0f); // exclusive
    }
    float s255 = sig * 255.0f;
    float w2 = -0.5f * LOG2E / (s255 * s255);
    float inten = intens[g];

    int t0x = mn[0] >> 3, t1x = (mx[0] - 1) >> 3;
    int t0y = mn[1] >> 3, t1y = (mx[1] - 1) >> 3;

    int tx = t0x + txi; if (tx > t1x) return;
    int ty = t0y + tyi; if (ty > t1y) return;

    int ox = tx << 3, oy = ty << 3;
    int lox = max(mn[0] - ox, 0), hix = min(mx[0] - ox, 8);
    int loy = max(mn[1] - oy, 0), hiy = min(mx[1] - oy, 8);

    // clipped, intensity-folded x-table (identical math to verified fat path)
    float ex[8];
    #pragma unroll
    for (int i = 0; i < 8; ++i) {
        float d = (float)(ox + i) - cx;
        float v = exp2f(d * d * w2) * inten;
        ex[i] = (i >= lox && i < hix) ? v : 0.0f;
    }

    int tzc = ((int)cz) >> 3;                  // cz in [0,255) -> tzc in [0,31]
    int t = (tx << 10) | (ty << 5) | tzc;
    unsigned meta = (unsigned)mn[2] | ((unsigned)(mx[2] - 1) << 8)
                  | ((unsigned)loy << 16) | ((unsigned)hiy << 19);

    int slot = atomicAdd(&counts[t], 1);
    if (slot < CAP) {
        int4* p = (int4*)&list[(size_t)t * CAP + slot];
        p[0] = make_int4(__float_as_int(cy), __float_as_int(cz),
                         __float_as_int(w2), (int)meta);
        p[1] = make_int4(__float_as_int(ex[0]), __float_as_int(ex[1]),
                         __float_as_int(ex[2]), __float_as_int(ex[3]));
        p[2] = make_int4(__float_as_int(ex[4]), __float_as_int(ex[5]),
                         __float_as_int(ex[6]), __float_as_int(ex[7]));
    }
}

// ---- kernel 2: gather — one wave per 4-tile z-chunk, LDS ring of slots -----
__global__ __launch_bounds__(256) void splat_main(
    const int*  __restrict__ counts,
    const Rec*  __restrict__ list,
    float* __restrict__ vol)
{
    // wave-private ring: 4 buffers x CAP records (3 int4) + 3 int4 pad for the
    // depth-2 prefetch overread. 4 waves * 4 * 99 * 16B = 25,344 B/block.
    __shared__ int4 ring[4][4][CAP * 3 + 3];

    int wid = threadIdx.x >> 6;
    int lane = threadIdx.x & 63;
    int u = __builtin_amdgcn_readfirstlane(blockIdx.x * 4 + wid);
    int tx = u >> 8, ty = (u >> 3) & 31, zc = u & 7;
    int colbase = (tx << 10) | (ty << 5);
    int z0 = zc << 2;                       // multiple of 4 -> static ring idx
    int ox = tx << 3, oy = ty << 3;
    int ly = lane >> 3, lz = lane & 7;
    float fy = (float)(oy + ly);

    auto ldc = [&](int s) -> int {
        if (s < 0 || s > 31) return 0;
        int c = counts[colbase + s];
        return c > CAP ? CAP : c;
    };
    int cA = ldc(z0 - 1), cB = ldc(z0), cC = ldc(z0 + 1);
    int cD = ldc(z0 + 2), cE = ldc(z0 + 3), cF = ldc(z0 + 4);

    auto stage_issue = [&](int s, int cnt, int4& v0, int4& v1) {
        int ch = 3 * cnt;
        const int4* src = (const int4*)(list + (size_t)(colbase + max(s, 0)) * CAP);
        if (lane < ch)      v0 = src[lane];
        if (lane + 64 < ch) v1 = src[lane + 64];
    };
    auto stage_write = [&](int rb, int cnt, int4 v0, int4 v1) {
        int ch = 3 * cnt;
        if (lane < ch)      ring[wid][rb][lane]      = v0;
        if (lane + 64 < ch) ring[wid][rb][lane + 64] = v1;
    };

    // record body — byte-identical math to R12
    auto proc = [&](int oz, float fz, int cnt, const int4* B, float (&acc)[8]) {
        if (cnt == 0) return;
        int4 a0 = B[0], a1 = B[1], a2 = B[2];
        for (int k = 0; k < cnt; ++k) {
            int b = (k + 1) * 3;
            int4 b0 = B[b], b1 = B[b + 1], b2 = B[b + 2];

            unsigned meta = (unsigned)__builtin_amdgcn_readfirstlane(a0.w);
            int mnz  = (int)(meta & 0xFF);
            int mxzi = (int)((meta >> 8) & 0xFF);
            int loz = mnz - oz;      if (loz < 0) loz = 0;
            int hiz = mxzi + 1 - oz; if (hiz > 8) hiz = 8;
            if (loz < hiz) {                       // wave-uniform z-overlap
                int loy_ = (int)((meta >> 16) & 7);
                int hiy_ = (int)((meta >> 19) & 0xF);   // in [1,8]
                ull ym = ((~0ull) << (loy_ << 3)) & ((~0ull) >> (64 - (hiy_ << 3)));
                unsigned zpat = (0xFFu >> (8 - hiz)) & (0xFFu << loz);
                unsigned zrep = zpat * 0x01010101u;
                ull m = (((ull)zrep << 32) | (ull)zrep) & ym;

                float cyv = __int_as_float(a0.x), czv = __int_as_float(a0.y);
                float w2v = __int_as_float(a0.z);

                float dy = fy - cyv, dz = fz - czv;
                float e = exp2f(fmaf(dy, dy, dz * dz) * w2v);
                float em;
                asm("v_cndmask_b32 %0, 0, %1, %2" : "=v"(em) : "v"(e), "s"(m));

                acc[0] = fmaf(__int_as_float(a1.x), em, acc[0]);
                acc[1] = fmaf(__int_as_float(a1.y), em, acc[1]);
                acc[2] = fmaf(__int_as_float(a1.z), em, acc[2]);
                acc[3] = fmaf(__int_as_float(a1.w), em, acc[3]);
                acc[4] = fmaf(__int_as_float(a2.x), em, acc[4]);
                acc[5] = fmaf(__int_as_float(a2.y), em, acc[5]);
                acc[6] = fmaf(__int_as_float(a2.z), em, acc[6]);
                acc[7] = fmaf(__int_as_float(a2.w), em, acc[7]);
            }
            a0 = b0; a1 = b1; a2 = b2;
        }
    };

    auto do_tile = [&](int tz, int cm, const int4* bm, int cc, const int4* bc,
                       int cp, const int4* bp) {
        int oz = tz << 3;
        float fz = (float)(oz + lz);
        float acc[8];
        #pragma unroll
        for (int i = 0; i < 8; ++i) acc[i] = 0.0f;
        proc(oz, fz, cm, bm, acc);
        proc(oz, fz, cc, bc, acc);
        proc(oz, fz, cp, bp, acc);
        int ybase = ((oy + ly) << 8) + (oz + lz);
        #pragma unroll
        for (int i = 0; i < 8; ++i)
            vol[((ox + i) << 16) + ybase] = acc[i];
    };

    // prologue: stage slots z0-1, z0, z0+1 into ring 3, 0, 1 (one exposed trip)
    {
        int4 av0 = {}, av1 = {}, bv0 = {}, bv1 = {}, cv0 = {}, cv1 = {};
        stage_issue(z0 - 1, cA, av0, av1);
        stage_issue(z0,     cB, bv0, bv1);
        stage_issue(z0 + 1, cC, cv0, cv1);
        stage_write(3, cA, av0, av1);
        stage_write(0, cB, bv0, bv1);
        stage_write(1, cC, cv0, cv1);
    }

    int4 s0v = {}, s1v = {};
    // step 0: issue slot z0+2 -> compute tile z0 -> write ring 2
    stage_issue(z0 + 2, cD, s0v, s1v);
    do_tile(z0 + 0, cA, ring[wid][3], cB, ring[wid][0], cC, ring[wid][1]);
    stage_write(2, cD, s0v, s1v);
    // step 1: issue slot z0+3 -> compute tile z0+1 -> write ring 3
    stage_issue(z0 + 3, cE, s0v, s1v);
    do_tile(z0 + 1, cB, ring[wid][0], cC, ring[wid][1], cD, ring[wid][2]);
    stage_write(3, cE, s0v, s1v);
    // step 2: issue slot z0+4 -> compute tile z0+2 -> write ring 0
    stage_issue(z0 + 4, cF, s0v, s1v);
    do_tile(z0 + 2, cC, ring[wid][1], cD, ring[wid][2], cE, ring[wid][3]);
    stage_write(0, cF, s0v, s1v);
    // step 3: compute tile z0+3 (no further staging)
    do_tile(z0 + 3, cD, ring[wid][2], cE, ring[wid][3], cF, ring[wid][0]);
}

// ---------------------------------------------------------------------------
extern "C" void kernel_launch(void* const* d_in, const int* in_sizes, int n_in,
                              void* d_out, int out_size, void* d_ws, size_t ws_size,
                              hipStream_t stream) {
    const float* centers = (const float*)d_in[0];   // (N,3)
    const float* sigmas  = (const float*)d_in[1];   // (N,)
    const float* intens  = (const float*)d_in[2];   // (N,)
    float* vol = (float*)d_out;                     // 256^3 fp32
    const int N = in_sizes[1];

    // workspace: counts 128KB | list NTILE*CAP*48B ~= 50.3 MiB
    char* ws = (char*)d_ws;
    int*  counts = (int*)ws;
    Rec*  list   = (Rec*)(ws + (size_t)NTILE * sizeof(int));

    hipMemsetAsync(counts, 0, (size_t)NTILE * sizeof(int), stream);

    int gblocks = (N + 255) / 256;
    bin_prep_kernel<<<dim3(gblocks, 9), 256, 0, stream>>>(centers, sigmas, intens,
                                                          counts, list, N);
    // 8192 z-chunk units (32x32 columns x 8 chunks), 4 waves per block
    splat_main<<<8192 / 4, 256, 0, stream>>>(counts, list, vol);
}

// Round 8
// 127.436 us; speedup vs baseline: 1.0496x; 1.0496x over previous
//
#include <hip/hip_runtime.h>

// ---------------------------------------------------------------------------
// 3-dispatch gather splat, COLUMN RECORDS, one wave per 8^3 tile.
// History: R7 fat records; R8 9x bin_prep split; R9 LDS staging; R10 atomic
// padding (NULL); R11 column records (bin_prep 39->30); R12 stored f32
// x-table (total 123.3, splat ~42); R13 z-chunk ring (REVERTED: vol writes
// lost the sibling-wave half-line pairing -> WRITE_SIZE 64->110MB, occupancy
// 35%; total 133.8). Wave->tile mapping t=bid*4+wid is LOAD-BEARING for
// write coalescing: 4 waves/block = consecutive tz, so 32B half-lines merge
// in L2 (measured exactly 64MB in R4).
// R14/R15: R12 base + depth-3 LDS record pipeline. R12 stalled ~60cy/record:
// depth-2 prefetch gives 1-body (~60cy) lookahead vs ~120cy ds_read latency
// (m117). Now records k,k+1 live in VGPRs and k+2's three ds_read_b128 issue
// before body(k) -> ~150cy lookahead. Stage loop issues both global-load
// rounds before the ds_writes. Math byte-identical to R12 => absmax same.
// (R15 = R14 resubmitted verbatim: round 7 bench was an infra failure, no
// counters produced.) ws use ~50.5 MB.
// ---------------------------------------------------------------------------

#define NTILE 32768           // 32^3 tiles of 8^3 voxels
#define CAP   32              // records per center-slot: avg ~7.7, Poisson-safe
#define LOG2E 1.4426950408889634f

typedef unsigned long long ull;

struct __align__(16) Rec {    // 48 B, one per (gaussian, x-y column)
    float cy, cz, w2;         // voxel-space center y,z; exp2 scale
    unsigned meta;            // [0:8) mnz, [8:16) mxz_incl, [16:19) loy, [19:23) hiy
    float ex[8];              // clipped, intensity-folded x-table (zeros outside)
};

// ---- kernel 1: per-(Gaussian, tx, ty) column record ------------------------
__global__ __launch_bounds__(256) void bin_prep_kernel(
    const float* __restrict__ centers,
    const float* __restrict__ sigmas,
    const float* __restrict__ intens,
    int*  __restrict__ counts,
    Rec*  __restrict__ list,
    int N)
{
    int g = blockIdx.x * 256 + threadIdx.x;
    if (g >= N) return;
    int txi = blockIdx.y % 3;          // wave-uniform
    int tyi = blockIdx.y / 3;

    float cx = centers[3*g+0] * 255.0f;
    float cy = centers[3*g+1] * 255.0f;
    float cz = centers[3*g+2] * 255.0f;
    float sig = sigmas[g];
    float cut = 3.0f * sig * 255.0f;
    float cc[3] = {cx, cy, cz};
    int mn[3], mx[3];
    #pragma unroll
    for (int a = 0; a < 3; ++a) {
        mn[a] = (int)floorf(fmaxf(cc[a] - cut, 0.0f));
        mx[a] = (int)fminf(floorf(fminf(cc[a] + cut, 255.0f)) + 1.0f, 256.0f); // exclusive
    }
    float s255 = sig * 255.0f;
    float w2 = -0.5f * LOG2E / (s255 * s255);
    float inten = intens[g];

    int t0x = mn[0] >> 3, t1x = (mx[0] - 1) >> 3;
    int t0y = mn[1] >> 3, t1y = (mx[1] - 1) >> 3;

    int tx = t0x + txi; if (tx > t1x) return;
    int ty = t0y + tyi; if (ty > t1y) return;

    int ox = tx << 3, oy = ty << 3;
    int lox = max(mn[0] - ox, 0), hix = min(mx[0] - ox, 8);
    int loy = max(mn[1] - oy, 0), hiy = min(mx[1] - oy, 8);

    // clipped, intensity-folded x-table (identical math to verified fat path)
    float ex[8];
    #pragma unroll
    for (int i = 0; i < 8; ++i) {
        float d = (float)(ox + i) - cx;
        float v = exp2f(d * d * w2) * inten;
        ex[i] = (i >= lox && i < hix) ? v : 0.0f;
    }

    int tzc = ((int)cz) >> 3;                  // cz in [0,255) -> tzc in [0,31]
    int t = (tx << 10) | (ty << 5) | tzc;
    unsigned meta = (unsigned)mn[2] | ((unsigned)(mx[2] - 1) << 8)
                  | ((unsigned)loy << 16) | ((unsigned)hiy << 19);

    int slot = atomicAdd(&counts[t], 1);
    if (slot < CAP) {
        int4* p = (int4*)&list[(size_t)t * CAP + slot];
        p[0] = make_int4(__float_as_int(cy), __float_as_int(cz),
                         __float_as_int(w2), (int)meta);
        p[1] = make_int4(__float_as_int(ex[0]), __float_as_int(ex[1]),
                         __float_as_int(ex[2]), __float_as_int(ex[3]));
        p[2] = make_int4(__float_as_int(ex[4]), __float_as_int(ex[5]),
                         __float_as_int(ex[6]), __float_as_int(ex[7]));
    }
}

// ---- kernel 2: gather — one wave per tile, scans center-slots tz-1..tz+1 ---
__global__ __launch_bounds__(256) void splat_main(
    const int*  __restrict__ counts,
    const Rec*  __restrict__ list,
    float* __restrict__ vol)
{
    // up to 3*CAP=96 records (3 int4 each = 288) + 2 pad records (prefetch
    // overread) -> 296 int4 = 4736 B/wave, 18.94 KB/block -> 8 blocks/CU.
    __shared__ int4 sh[4][296];

    int wid = threadIdx.x >> 6;
    int lane = threadIdx.x & 63;
    int t = __builtin_amdgcn_readfirstlane(blockIdx.x * 4 + wid);
    int ox = (t >> 10) << 3, oy = ((t >> 5) & 31) << 3, oz = (t & 31) << 3;
    int tz = t & 31;
    int ly = lane >> 3, lz = lane & 7;

    int c0 = (tz > 0)  ? counts[t - 1] : 0;  if (c0 > CAP) c0 = CAP;
    int c1 = counts[t];                       if (c1 > CAP) c1 = CAP;
    int c2 = (tz < 31) ? counts[t + 1] : 0;  if (c2 > CAP) c2 = CAP;
    int n01 = c0 + c1, ntot = n01 + c2;

    const int4* sA = (const int4*)(list + (long)(t - 1) * CAP);  // unused if c0==0
    const int4* sB = (const int4*)(list + (long)t * CAP);
    const int4* sC = (const int4*)(list + (long)(t + 1) * CAP);

    int e0 = 3 * c0, e1 = 3 * n01, etot = 3 * ntot;

    auto pick = [&](int k) -> int4 {
        const int4* src; int off;
        if (k < e0)      { src = sA; off = k; }
        else if (k < e1) { src = sB; off = k - e0; }
        else             { src = sC; off = k - e1; }
        return src[off];
    };

    // stage: issue both rounds' loads before the ds_writes (etot <= 128
    // covers all but Poisson-tail tiles; rare 3rd+ rounds in the loop).
    {
        bool b0 = lane < etot, b1 = lane + 64 < etot;
        int4 v0, v1;
        if (b0) v0 = pick(lane);
        if (b1) v1 = pick(lane + 64);
        if (b0) sh[wid][lane]      = v0;
        if (b1) sh[wid][lane + 64] = v1;
        for (int k = lane + 128; k < etot; k += 64)
            sh[wid][k] = pick(k);
    }

    float fy = (float)(oy + ly);
    float fz = (float)(oz + lz);

    float acc[8];
    #pragma unroll
    for (int i = 0; i < 8; ++i) acc[i] = 0.0f;

    const int4* P = sh[wid];

    auto body = [&](int4 a0, int4 a1, int4 a2) {
        unsigned meta = (unsigned)__builtin_amdgcn_readfirstlane(a0.w);
        int mnz  = (int)(meta & 0xFF);
        int mxzi = (int)((meta >> 8) & 0xFF);
        int loz = mnz - oz;      if (loz < 0) loz = 0;
        int hiz = mxzi + 1 - oz; if (hiz > 8) hiz = 8;
        if (loz < hiz) {                       // wave-uniform z-overlap branch
            int loy_ = (int)((meta >> 16) & 7);
            int hiy_ = (int)((meta >> 19) & 0xF);   // in [1,8]
            ull ym = ((~0ull) << (loy_ << 3)) & ((~0ull) >> (64 - (hiy_ << 3)));
            unsigned zpat = (0xFFu >> (8 - hiz)) & (0xFFu << loz);
            unsigned zrep = zpat * 0x01010101u;
            ull m = (((ull)zrep << 32) | (ull)zrep) & ym;

            float cyv = __int_as_float(a0.x), czv = __int_as_float(a0.y);
            float w2v = __int_as_float(a0.z);

            float dy = fy - cyv, dz = fz - czv;
            float e = exp2f(fmaf(dy, dy, dz * dz) * w2v);
            float em;
            asm("v_cndmask_b32 %0, 0, %1, %2" : "=v"(em) : "v"(e), "s"(m));

            acc[0] = fmaf(__int_as_float(a1.x), em, acc[0]);
            acc[1] = fmaf(__int_as_float(a1.y), em, acc[1]);
            acc[2] = fmaf(__int_as_float(a1.z), em, acc[2]);
            acc[3] = fmaf(__int_as_float(a1.w), em, acc[3]);
            acc[4] = fmaf(__int_as_float(a2.x), em, acc[4]);
            acc[5] = fmaf(__int_as_float(a2.y), em, acc[5]);
            acc[6] = fmaf(__int_as_float(a2.z), em, acc[6]);
            acc[7] = fmaf(__int_as_float(a2.w), em, acc[7]);
        }
    };

    // depth-3 record pipeline: records k (A) and k+1 (B) in registers,
    // record k+2 (C) issued before body(k) -> ~2-body lookahead >= ds_read
    // latency (~120cy). Pad records keep the overread in-bounds.
    int4 A0 = P[0], A1 = P[1], A2 = P[2];
    int4 B0 = P[3], B1 = P[4], B2 = P[5];
    for (int k = 0; k < ntot; ++k) {
        int c = (k + 2) * 3;
        int4 C0 = P[c], C1 = P[c + 1], C2 = P[c + 2];
        body(A0, A1, A2);
        A0 = B0; A1 = B1; A2 = B2;
        B0 = C0; B1 = C1; B2 = C2;
    }

    int ybase = ((oy + ly) << 8) + (oz + lz);
    #pragma unroll
    for (int i = 0; i < 8; ++i)
        vol[((ox + i) << 16) + ybase] = acc[i];
}

// ---------------------------------------------------------------------------
extern "C" void kernel_launch(void* const* d_in, const int* in_sizes, int n_in,
                              void* d_out, int out_size, void* d_ws, size_t ws_size,
                              hipStream_t stream) {
    const float* centers = (const float*)d_in[0];   // (N,3)
    const float* sigmas  = (const float*)d_in[1];   // (N,)
    const float* intens  = (const float*)d_in[2];   // (N,)
    float* vol = (float*)d_out;                     // 256^3 fp32
    const int N = in_sizes[1];

    // workspace: counts 128KB | list NTILE*CAP*48B ~= 50.3 MiB
    char* ws = (char*)d_ws;
    int*  counts = (int*)ws;
    Rec*  list   = (Rec*)(ws + (size_t)NTILE * sizeof(int));

    hipMemsetAsync(counts, 0, (size_t)NTILE * sizeof(int), stream);

    int gblocks = (N + 255) / 256;
    bin_prep_kernel<<<dim3(gblocks, 9), 256, 0, stream>>>(centers, sigmas, intens,
                                                          counts, list, N);
    splat_main<<<NTILE / 4, 256, 0, stream>>>(counts, list, vol);
}